// Round 1
// baseline (48.703 us; speedup 1.0000x reference)
//
#include <hip/hip_runtime.h>
#include <hip/hip_bf16.h>

// y[b,i] = out[b,i] if lower[i] <= (out[b,i] - out[b,(i-1)%N]) <= upper[i] else 0
// where out = NaN/Inf-sanitized input, lower/upper = mean_grad -/+ k*sqrt(var_grad).
// Memory-bound: 134 MB read + 134 MB write -> ~43 us floor at 6.3 TB/s.

__device__ __forceinline__ float sanitize(float x) {
    // NaN or Inf  <=>  exponent bits all ones
    unsigned u = __float_as_uint(x);
    return ((u & 0x7f800000u) == 0x7f800000u) ? 0.0f : x;
}

__global__ __launch_bounds__(256) void correction_kernel(
    const float* __restrict__ in,
    const float* __restrict__ mean_grad,
    const float* __restrict__ var_grad,
    const int* __restrict__ kptr,
    float* __restrict__ y,
    int N)
{
    const int row = blockIdx.x;
    const float kf = (float)(*kptr);   // scalar load, broadcast
    const float* __restrict__ rp = in + (size_t)row * (size_t)N;
    float* __restrict__ ro = y + (size_t)row * (size_t)N;
    const int vec_per_row = N >> 2;

    for (int v = threadIdx.x; v < vec_per_row; v += blockDim.x) {
        const int i = v << 2;
        float4 x = *reinterpret_cast<const float4*>(rp + i);
        float prev = rp[(i == 0) ? (N - 1) : (i - 1)];   // circular, L1-hit

        float s0 = sanitize(x.x);
        float s1 = sanitize(x.y);
        float s2 = sanitize(x.z);
        float s3 = sanitize(x.w);
        float sp = sanitize(prev);

        float4 m  = *reinterpret_cast<const float4*>(mean_grad + i);
        float4 vr = *reinterpret_cast<const float4*>(var_grad + i);

        // k=4 is a power of two: kf*sqrtf() is exact after the correctly
        // rounded sqrt, so lo/hi match NumPy bit-for-bit (single rounding).
        float t0 = kf * sqrtf(vr.x);
        float t1 = kf * sqrtf(vr.y);
        float t2 = kf * sqrtf(vr.z);
        float t3 = kf * sqrtf(vr.w);

        float d0 = s0 - sp;
        float d1 = s1 - s0;
        float d2 = s2 - s1;
        float d3 = s3 - s2;

        float r0 = (d0 < m.x - t0 || d0 > m.x + t0) ? 0.0f : s0;
        float r1 = (d1 < m.y - t1 || d1 > m.y + t1) ? 0.0f : s1;
        float r2 = (d2 < m.z - t2 || d2 > m.z + t2) ? 0.0f : s2;
        float r3 = (d3 < m.w - t3 || d3 > m.w + t3) ? 0.0f : s3;

        *reinterpret_cast<float4*>(ro + i) = make_float4(r0, r1, r2, r3);
    }
}

extern "C" void kernel_launch(void* const* d_in, const int* in_sizes, int n_in,
                              void* d_out, int out_size, void* d_ws, size_t ws_size,
                              hipStream_t stream) {
    const float* in        = (const float*)d_in[0];
    const float* mean_grad = (const float*)d_in[1];
    const float* var_grad  = (const float*)d_in[2];
    const int*   kptr      = (const int*)d_in[3];
    float* y = (float*)d_out;

    const int N = in_sizes[1];              // 8192
    const int B = in_sizes[0] / N;          // 4096

    dim3 grid(B);
    dim3 block(256);
    correction_kernel<<<grid, block, 0, stream>>>(in, mean_grad, var_grad, kptr, y, N);
}

// Round 3
// 44.819 us; speedup vs baseline: 1.0867x; 1.0867x over previous
//
#include <hip/hip_runtime.h>
#include <hip/hip_bf16.h>

// y[b,i] = out[b,i] if lower[i] <= (out[b,i] - out[b,(i-1)%N]) <= upper[i] else 0
// where out = NaN/Inf-sanitized input, lower/upper = mean_grad -/+ k*sqrt(var_grad).
// Memory-bound. Round-3: non-temporal output stores via native clang vector
// type (HIP_vector_type<float,4> is rejected by the builtin; ext_vector_type
// is accepted and lowers to global_store_dwordx4 ... nt).

typedef float f32x4 __attribute__((ext_vector_type(4)));

__device__ __forceinline__ float sanitize(float x) {
    // NaN or Inf  <=>  exponent bits all ones
    unsigned u = __float_as_uint(x);
    return ((u & 0x7f800000u) == 0x7f800000u) ? 0.0f : x;
}

__global__ __launch_bounds__(256) void correction_kernel(
    const float* __restrict__ in,
    const float* __restrict__ mean_grad,
    const float* __restrict__ var_grad,
    const int* __restrict__ kptr,
    float* __restrict__ y,
    int N)
{
    const int row = blockIdx.x;
    const float kf = (float)(*kptr);   // scalar load, broadcast
    const float* __restrict__ rp = in + (size_t)row * (size_t)N;
    float* __restrict__ ro = y + (size_t)row * (size_t)N;
    const int vec_per_row = N >> 2;

    for (int v = threadIdx.x; v < vec_per_row; v += blockDim.x) {
        const int i = v << 2;
        f32x4 x = *reinterpret_cast<const f32x4*>(rp + i);
        float prev = rp[(i == 0) ? (N - 1) : (i - 1)];   // circular, L1-hit

        float s0 = sanitize(x.x);
        float s1 = sanitize(x.y);
        float s2 = sanitize(x.z);
        float s3 = sanitize(x.w);
        float sp = sanitize(prev);

        f32x4 m  = *reinterpret_cast<const f32x4*>(mean_grad + i);
        f32x4 vr = *reinterpret_cast<const f32x4*>(var_grad + i);

        // k=4 is a power of two: kf*sqrtf() is exact after the correctly
        // rounded sqrt, so lo/hi match NumPy bit-for-bit (single rounding).
        float t0 = kf * sqrtf(vr.x);
        float t1 = kf * sqrtf(vr.y);
        float t2 = kf * sqrtf(vr.z);
        float t3 = kf * sqrtf(vr.w);

        float d0 = s0 - sp;
        float d1 = s1 - s0;
        float d2 = s2 - s1;
        float d3 = s3 - s2;

        f32x4 r;
        r.x = (d0 < m.x - t0 || d0 > m.x + t0) ? 0.0f : s0;
        r.y = (d1 < m.y - t1 || d1 > m.y + t1) ? 0.0f : s1;
        r.z = (d2 < m.z - t2 || d2 > m.z + t2) ? 0.0f : s2;
        r.w = (d3 < m.w - t3 || d3 > m.w + t3) ? 0.0f : s3;

        // Stream past L2/L3: output is write-once, never re-read.
        __builtin_nontemporal_store(r, reinterpret_cast<f32x4*>(ro + i));
    }
}

extern "C" void kernel_launch(void* const* d_in, const int* in_sizes, int n_in,
                              void* d_out, int out_size, void* d_ws, size_t ws_size,
                              hipStream_t stream) {
    const float* in        = (const float*)d_in[0];
    const float* mean_grad = (const float*)d_in[1];
    const float* var_grad  = (const float*)d_in[2];
    const int*   kptr      = (const int*)d_in[3];
    float* y = (float*)d_out;

    const int N = in_sizes[1];              // 8192
    const int B = in_sizes[0] / N;          // 4096

    dim3 grid(B);
    dim3 block(256);
    correction_kernel<<<grid, block, 0, stream>>>(in, mean_grad, var_grad, kptr, y, N);
}